// Round 3
// baseline (482.657 us; speedup 1.0000x reference)
//
#include <hip/hip_runtime.h>
#include <math.h>

#define BSZ 256
#define DIM 1024
#define VOC 50257
#define NL 2
#define NB 8
#define DH 128

typedef __bf16 bf16x8 __attribute__((ext_vector_type(8)));
typedef float  f32x4  __attribute__((ext_vector_type(4)));
typedef unsigned short u16;
typedef u16 u16x8 __attribute__((ext_vector_type(8)));

__device__ __forceinline__ u16 f2bf(float f) {
  unsigned int u = __float_as_uint(f);
  u += 0x7fffu + ((u >> 16) & 1u);   // RNE
  return (u16)(u >> 16);
}
__device__ __forceinline__ float sigm(float x) { return 1.0f / (1.0f + __expf(-x)); }

// ---------------------------------------------------------------------------
// Barrier-free per-wave GEMM: acc[M16][N16] += A(bf16, row-major lda) *
// B(fp32, row-major ldb)^T. Fragments loaded directly from global in MFMA
// operand layout. 4-stage register pipeline. Requires K % 128 == 0.
// ---------------------------------------------------------------------------
template<int M16, int N16, int K, bool CLAMPN>
__device__ __forceinline__ void wave_gemm(
    const u16* __restrict__ A, int lda,
    const float* __restrict__ B, int ldb, int nClamp,
    f32x4 (&acc)[M16][N16])
{
  const int lane = threadIdx.x & 63;
  const int quad = lane >> 4;
  const int l16  = lane & 15;

  const u16* aR[M16];
  const float* bR[N16];
#pragma unroll
  for (int mi = 0; mi < M16; ++mi)
    aR[mi] = A + (long)(mi * 16 + l16) * lda + quad * 8;
#pragma unroll
  for (int ni = 0; ni < N16; ++ni) {
    int n = ni * 16 + l16;
    if (CLAMPN) n = n > nClamp ? nClamp : n;   // clamp addr; result discarded
    bR[ni] = B + (long)n * ldb + quad * 8;
  }

  bf16x8 aF[4][M16];
  bf16x8 bF[4][N16];

#define WG_LOAD(kk, buf)                                                  \
  {                                                                       \
    _Pragma("unroll")                                                     \
    for (int ni = 0; ni < N16; ++ni) {                                    \
      float4 v0 = *(const float4*)(bR[ni] + (kk));                        \
      float4 v1 = *(const float4*)(bR[ni] + (kk) + 4);                    \
      u16x8 h;                                                            \
      h[0] = f2bf(v0.x); h[1] = f2bf(v0.y);                               \
      h[2] = f2bf(v0.z); h[3] = f2bf(v0.w);                               \
      h[4] = f2bf(v1.x); h[5] = f2bf(v1.y);                               \
      h[6] = f2bf(v1.z); h[7] = f2bf(v1.w);                               \
      bF[buf][ni] = __builtin_bit_cast(bf16x8, h);                        \
    }                                                                     \
    _Pragma("unroll")                                                     \
    for (int mi = 0; mi < M16; ++mi)                                      \
      aF[buf][mi] = *(const bf16x8*)(aR[mi] + (kk));                      \
  }

#define WG_MM(buf)                                                        \
  {                                                                       \
    _Pragma("unroll")                                                     \
    for (int mi = 0; mi < M16; ++mi)                                      \
      _Pragma("unroll")                                                   \
      for (int ni = 0; ni < N16; ++ni)                                    \
        acc[mi][ni] = __builtin_amdgcn_mfma_f32_16x16x32_bf16(            \
            aF[buf][mi], bF[buf][ni], acc[mi][ni], 0, 0, 0);              \
  }

  WG_LOAD(0, 0);
  WG_LOAD(32, 1);
  WG_LOAD(64, 2);
#pragma unroll 1
  for (int kk = 0; kk < K - 128; kk += 128) {
    WG_LOAD(kk + 96, 3);  WG_MM(0);
    WG_LOAD(kk + 128, 0); WG_MM(1);
    WG_LOAD(kk + 160, 1); WG_MM(2);
    WG_LOAD(kk + 192, 2); WG_MM(3);
  }
  WG_LOAD(K - 32, 3);
  WG_MM(0); WG_MM(1); WG_MM(2); WG_MM(3);
#undef WG_LOAD
#undef WG_MM
}

// A-operand from LDS (16 rows x 128 k, bf16, XOR-swizzled), B fp32 from
// global (rows l16 of a [16][ldb] strip). M16=N16=1, K=128.
__device__ __forceinline__ void wave_gemm_ldsA(
    const u16* S, const float* __restrict__ B, int ldb, f32x4& acc,
    int l16, int quad)
{
  const float* bR = B + (long)l16 * ldb + quad * 8;
#pragma unroll
  for (int c = 0; c < 4; ++c) {
    bf16x8 af = *(const bf16x8*)((const char*)S + l16 * 256 +
                                 ((c * 64 + quad * 16) ^ ((l16 & 7) << 4)));
    float4 v0 = *(const float4*)(bR + c * 32);
    float4 v1 = *(const float4*)(bR + c * 32 + 4);
    u16x8 h;
    h[0] = f2bf(v0.x); h[1] = f2bf(v0.y);
    h[2] = f2bf(v0.z); h[3] = f2bf(v0.w);
    h[4] = f2bf(v1.x); h[5] = f2bf(v1.y);
    h[6] = f2bf(v1.z); h[7] = f2bf(v1.w);
    acc = __builtin_amdgcn_mfma_f32_16x16x32_bf16(
        af, __builtin_bit_cast(bf16x8, h), acc, 0, 0, 0);
  }
}

#define ACC_DECL(N16V)                                \
  f32x4 acc[4][N16V];                                 \
  { f32x4 z = {0.f, 0.f, 0.f, 0.f};                   \
    _Pragma("unroll")                                 \
    for (int i = 0; i < 4; ++i)                       \
      _Pragma("unroll")                               \
      for (int j = 0; j < N16V; ++j) acc[i][j] = z; }

// ---------------------------------------------------------------------------
// K1: carry (bool-layout detect), x gather, h->bf16, + LLC warm of all weights
// ---------------------------------------------------------------------------
__global__ __launch_bounds__(256) void k_prep(
    const int* __restrict__ ids, const void* __restrict__ mask,
    const float* __restrict__ emb, const float* __restrict__ hstate,
    const float* __restrict__ W_alpha, const float* __restrict__ W_in,
    const float* __restrict__ W_wm_out, const float* __restrict__ W_x,
    const float* __restrict__ W_h, const float* __restrict__ W_wml,
    const float* __restrict__ W_g,
    float* __restrict__ xout, u16* __restrict__ x_bf,
    u16* __restrict__ h_bf, float* __restrict__ carry, float* __restrict__ sink)
{
  __shared__ int sInt;
  const int tid = threadIdx.x, s = blockIdx.x;
  if (tid == 0) sInt = 1;
  __syncthreads();
  if (tid < 64) {
    int v = ((const int*)mask)[tid];
    if (v != 0 && v != 1) atomicAnd(&sInt, 0);
  }
  __syncthreads();
  if (tid == 0) {
    int m = sInt ? ((const int*)mask)[s] : (int)((const unsigned char*)mask)[s];
    carry[s] = m ? 0.0f : 1.0f;
  }
  long id = ids[s];
  int k = tid * 4;
  float4 v = *(const float4*)(emb + id * DIM + k);
  *(float4*)(xout + (long)s * DIM + k) = v;
  ushort4 h; h.x = f2bf(v.x); h.y = f2bf(v.y); h.z = f2bf(v.z); h.w = f2bf(v.w);
  *(ushort4*)(x_bf + (long)s * DIM + k) = h;
#pragma unroll
  for (int l = 0; l < NL; ++l) {
    long off = (long)l * BSZ * DIM + (long)s * DIM + k;
    float4 w = *(const float4*)(hstate + off);
    ushort4 o; o.x = f2bf(w.x); o.y = f2bf(w.y); o.z = f2bf(w.z); o.w = f2bf(w.w);
    *(ushort4*)(h_bf + off) = o;
  }
  // ---- LLC warm (loads can't be eliminated; branch never taken) ----
  long gtid = (long)blockIdx.x * 256 + tid;
  long gstride = (long)gridDim.x * 256;
  float acc = 0.f;
  {
    const long nDD = (long)DIM * DIM / 4;       // 1024x1024 f32 -> float4 count
    for (long i = gtid; i < nDD; i += gstride) {
      float4 a = ((const float4*)W_alpha)[i];
      float4 b = ((const float4*)W_in)[i];
      float4 c = ((const float4*)W_wm_out)[i];
      acc += a.x + a.w + b.x + b.w + c.x + c.w;
    }
    const long nS = (long)NL * NB * DH * DH / 4;
    for (long i = gtid; i < nS; i += gstride) {
      float4 a = ((const float4*)W_x)[i];
      float4 b = ((const float4*)W_h)[i];
      float4 c = ((const float4*)W_g)[i];
      acc += a.x + a.w + b.x + b.w + c.x + c.w;
    }
    const long nW = (long)NL * NB * DH * DIM / 4;
    for (long i = gtid; i < nW; i += gstride) {
      float4 a = ((const float4*)W_wml)[i];
      acc += a.x + a.w;
    }
  }
  if (acc == -1.17521e35f) *sink = acc;   // never true in practice; defeats DCE
}

// ---------------------------------------------------------------------------
// K2: [alpha_pre | x_proj] = x @ [W_alpha ; W_in]^T, fused wm_new epilogue
// 512 blocks x 64 threads: m-slice = blk&3, n-tile16 = blk>>2 (128 tiles)
// ---------------------------------------------------------------------------
__global__ __launch_bounds__(64) void k_gemm1(
    const u16* __restrict__ x_bf,
    const float* __restrict__ W_alpha, const float* __restrict__ W_in,
    const float* __restrict__ carry, const float* __restrict__ wm_state,
    const float* __restrict__ xout,
    u16* __restrict__ wm_bf, u16* __restrict__ cur_bf)
{
  const int tid = threadIdx.x, quad = tid >> 4, l16 = tid & 15;
  const int m = blockIdx.x & 3;
  const int nt = blockIdx.x >> 2;
  const bool isAlpha = nt < 64;
  const int n0 = (isAlpha ? nt : nt - 64) * 16;
  ACC_DECL(1)
  wave_gemm<4, 1, DIM, false>(x_bf + (long)m * 64 * DIM, DIM,
                              (isAlpha ? W_alpha : W_in) + (long)n0 * DIM, DIM, 0, acc);
#pragma unroll
  for (int mi = 0; mi < 4; ++mi) {
    int n = n0 + l16;
#pragma unroll
    for (int r = 0; r < 4; ++r) {
      int s = m * 64 + mi * 16 + quad * 4 + r;
      float c = acc[mi][0][r];
      long idx = (long)s * DIM + n;
      if (isAlpha) wm_bf[idx] = f2bf(carry[s] * sigm(c) * wm_state[idx] + xout[idx]);
      else         cur_bf[idx] = f2bf(c);
    }
  }
}

// ---------------------------------------------------------------------------
// K3: y_wm = tanh(wm_new @ W_wm_out^T)   (256 blocks x 64 threads)
// ---------------------------------------------------------------------------
__global__ __launch_bounds__(64) void k_gemm2(
    const u16* __restrict__ wm_bf, const float* __restrict__ W_wm_out,
    float* __restrict__ yout, u16* __restrict__ ywm_bf)
{
  const int tid = threadIdx.x, quad = tid >> 4, l16 = tid & 15;
  const int m = blockIdx.x & 3;
  const int n0 = (blockIdx.x >> 2) * 16;
  ACC_DECL(1)
  wave_gemm<4, 1, DIM, false>(wm_bf + (long)m * 64 * DIM, DIM,
                              W_wm_out + (long)n0 * DIM, DIM, 0, acc);
#pragma unroll
  for (int mi = 0; mi < 4; ++mi) {
    int n = n0 + l16;
#pragma unroll
    for (int r = 0; r < 4; ++r) {
      int s = m * 64 + mi * 16 + quad * 4 + r;
      float y = tanhf(acc[mi][0][r]);
      long idx = (long)s * DIM + n;
      yout[idx] = y;
      ywm_bf[idx] = f2bf(y);
    }
  }
}

// ---------------------------------------------------------------------------
// K4 (fused layers): the whole 2-layer recurrence. Key fact: after y_wm,
// the chain cur->a->g->h_new->cur is b-local (all einsums contract within
// one b; only y_wm's K=1024 term crosses, and y_wm is fixed input here).
// Grid: 128 blocks = 16 m-slices (16 rows) x 8 b. 8 waves/block, wave w
// owns e-tile [w*16, w*16+16). a and h_new live in one 4 KB LDS tile
// (XOR-swizzled [16 rows][128 cols] bf16) with barrier discipline:
//   stage cur -> S; bar
//   per layer: phaseA(W_x from S, W_h, W_wml) ; bar ; a->S ; bar ;
//              phaseG(W_g from S) ; epilogue ; bar ; h_new->S ; bar
// Numerics identical to the old 4-dispatch path (same f2bf points).
// ---------------------------------------------------------------------------
__global__ __launch_bounds__(512) void k_layers(
    const u16* __restrict__ cur_bf, const u16* __restrict__ h_bf,
    const u16* __restrict__ ywm_bf,
    const float* __restrict__ W_x, const float* __restrict__ W_h,
    const float* __restrict__ W_wml, const float* __restrict__ W_g,
    const float* __restrict__ w_s, const float* __restrict__ b_g,
    const float* __restrict__ surprise, const float* __restrict__ carry,
    const float* __restrict__ hstate,
    u16* __restrict__ hfin_bf)
{
  __shared__ u16 S[16 * 128];             // 4 KB tile, rows at 256 B stride
  const int tid  = threadIdx.x;
  const int wv   = tid >> 6;              // 0..7 = e-tile
  const int lane = tid & 63;
  const int quad = lane >> 4, l16 = lane & 15;
  const int m  = blockIdx.x & 15;         // 16 m-slices of 16 rows
  const int b  = blockIdx.x >> 4;         // 0..7
  const int e0 = wv * 16;
  const int row0 = m * 16;

  // stage cur slice (rows row0..+15, cols b*128..+127) into S
  {
    const int r  = tid >> 5;              // 0..15
    const int c8 = (tid & 31) * 8;        // byte col, step 8
    uint2 v = *(const uint2*)((const char*)(cur_bf + (long)(row0 + r) * DIM + b * DH) + c8);
    *(uint2*)((char*)S + r * 256 + (c8 ^ ((r & 7) << 4))) = v;
  }
  __syncthreads();

#pragma unroll 1
  for (int l = 0; l < NL; ++l) {
    const long wb = (long)(l * NB + b) * DH;
    // ---- phase A: a = cur@W_x^T + h@W_h^T + ywm@W_wml^T (16-col strip) ----
    f32x4 aacc[1][1];
    { f32x4 z = {0.f, 0.f, 0.f, 0.f}; aacc[0][0] = z; }
    wave_gemm_ldsA(S, W_x + (wb + e0) * DH, DH, aacc[0][0], l16, quad);
    wave_gemm<1, 1, DH, false>(h_bf + (long)l * BSZ * DIM + (long)row0 * DIM + b * DH, DIM,
                               W_h + (wb + e0) * DH, DH, 0, aacc);
    wave_gemm<1, 1, DIM, false>(ywm_bf + (long)row0 * DIM, DIM,
                                W_wml + (wb + e0) * DIM, DIM, 0, aacc);
    __syncthreads();                      // all waves done reading S (cur)
    // write a (bf16) into S; keep fp32 in regs for tanh
#pragma unroll
    for (int r = 0; r < 4; ++r) {
      int row = quad * 4 + r;
      *(u16*)((char*)S + row * 256 + (((e0 + l16) * 2) ^ ((row & 7) << 4))) =
          f2bf(aacc[0][0][r]);
    }
    __syncthreads();
    // ---- phase G: g_pre = a@W_g^T ----
    f32x4 gacc = {0.f, 0.f, 0.f, 0.f};
    wave_gemm_ldsA(S, W_g + (wb + e0) * DH, DH, gacc, l16, quad);
    // ---- epilogue: h_new = carry * ((1-g)*h + g*tanh(a)) ----
    const int col = e0 + l16;
    const float ws_v = w_s[wb + col];
    const float bg_v = b_g[wb + col];
    float hn[4];
#pragma unroll
    for (int r = 0; r < 4; ++r) {
      int s = row0 + quad * 4 + r;
      float g = sigm(gacc[r] + surprise[s] * ws_v + bg_v);
      float ho = hstate[(long)l * BSZ * DIM + (long)s * DIM + b * DH + col];
      hn[r] = carry[s] * ((1.0f - g) * ho + g * tanhf(aacc[0][0][r]));
    }
    __syncthreads();                      // all waves done reading S (a)
#pragma unroll
    for (int r = 0; r < 4; ++r) {
      int row = quad * 4 + r;
      u16 hv = f2bf(hn[r]);
      *(u16*)((char*)S + row * 256 + ((col * 2) ^ ((row & 7) << 4))) = hv;
      if (l == NL - 1)
        hfin_bf[(long)(row0 + row) * DIM + b * DH + col] = hv;
    }
    __syncthreads();                      // h_new visible as next layer's cur
  }
}

// ---------------------------------------------------------------------------
// K8: logits = h_final @ emb^T — LDS-staged, single barrier per K-tile,
// 2-deep register staging. 786 blocks x 256 threads (4 waves), 64 cols each.
// Loads for tile t+3 are issued at iter t (named P/Q reg sets, loop
// unrolled x2) and converted->LDS at iter t+2: ~2 full iterations of HBM
// latency cover, 32 KB/block outstanding steady-state (vs 16 KB before —
// R2's counters showed staging duty-cycle, not BW, limits this kernel).
// ---------------------------------------------------------------------------
__global__ __launch_bounds__(256) void k_logits_lds(
    const u16* __restrict__ hfin_bf, const float* __restrict__ emb,
    float* __restrict__ out)
{
  __shared__ u16 Bs[2][64 * 64];          // 2 x 8 KB bf16 tiles
  const int tid  = threadIdx.x;
  const int wave = tid >> 6;
  const int lane = tid & 63;
  const int quad = lane >> 4;
  const int l16  = lane & 15;
  const int n0   = blockIdx.x * 64;

  // --- staging map: thread -> (row 0..63, 16 f32 at col scol..scol+15) ---
  const int srow = tid >> 2;              // 0..63
  const int scol = (tid & 3) * 16;        // f32 col: 0,16,32,48
  long gn = n0 + srow;
  if (gn >= VOC) gn = VOC - 1;            // tail clamp; dup values discarded on store
  const float* src = emb + gn * DIM + scol;
  const int sw  = (srow & 7) << 4;
  const int sb0 = srow * 128 + ((scol * 2) ^ sw);
  const int sb1 = srow * 128 + (((scol * 2) + 16) ^ sw);

  // --- A fragment pointers (hfin_bf is 512 KB, L2-resident in every XCD) ---
  const u16* aP[4];
#pragma unroll
  for (int mi = 0; mi < 4; ++mi)
    aP[mi] = hfin_bf + (long)(wave * 64 + mi * 16 + l16) * DIM + quad * 8;

  f32x4 acc[4][4];
  { f32x4 z = {0.f, 0.f, 0.f, 0.f};
#pragma unroll
    for (int mi = 0; mi < 4; ++mi)
#pragma unroll
      for (int ni = 0; ni < 4; ++ni) acc[mi][ni] = z; }

  float4 P0, P1, P2, P3, Q0, Q1, Q2, Q3;
#define LDP(t)                                                            \
  { P0 = *(const float4*)(src + (t) * 64);                                \
    P1 = *(const float4*)(src + (t) * 64 + 4);                            \
    P2 = *(const float4*)(src + (t) * 64 + 8);                            \
    P3 = *(const float4*)(src + (t) * 64 + 12); }
#define LDQ(t)                                                            \
  { Q0 = *(const float4*)(src + (t) * 64);                                \
    Q1 = *(const float4*)(src + (t) * 64 + 4);                            \
    Q2 = *(const float4*)(src + (t) * 64 + 8);                            \
    Q3 = *(const float4*)(src + (t) * 64 + 12); }
#define CVT_WR(bufi, a, bq, c, d)                                         \
  { u16x8 h0, h1;                                                         \
    h0[0] = f2bf(a.x); h0[1] = f2bf(a.y);                                 \
    h0[2] = f2bf(a.z); h0[3] = f2bf(a.w);                                 \
    h0[4] = f2bf(bq.x); h0[5] = f2bf(bq.y);                               \
    h0[6] = f2bf(bq.z); h0[7] = f2bf(bq.w);                               \
    h1[0] = f2bf(c.x); h1[1] = f2bf(c.y);                                 \
    h1[2] = f2bf(c.z); h1[3] = f2bf(c.w);                                 \
    h1[4] = f2bf(d.x); h1[5] = f2bf(d.y);                                 \
    h1[6] = f2bf(d.z); h1[7] = f2bf(d.w);                                 \
    *(u16x8*)((char*)&Bs[bufi][0] + sb0) = h0;                            \
    *(u16x8*)((char*)&Bs[bufi][0] + sb1) = h1; }
#define COMPUTE(t, bufi)                                                  \
  { const char* bb = (const char*)&Bs[bufi][0];                           \
    const int k0 = (t) * 64;                                              \
    bf16x8 aF0[4], aF1[4], bF0[4], bF1[4];                                \
    _Pragma("unroll")                                                     \
    for (int mi = 0; mi < 4; ++mi) aF0[mi] = *(const bf16x8*)(aP[mi] + k0);\
    _Pragma("unroll")                                                     \
    for (int mi = 0; mi < 4; ++mi) aF1[mi] = *(const bf16x8*)(aP[mi] + k0 + 32);\
    _Pragma("unroll")                                                     \
    for (int ni = 0; ni < 4; ++ni) {                                      \
      const int row = ni * 16 + l16;                                      \
      const int ib0 = (quad * 16) ^ ((row & 7) << 4);                     \
      bF0[ni] = *(const bf16x8*)(bb + row * 128 + ib0);                   \
      bF1[ni] = *(const bf16x8*)(bb + row * 128 + (ib0 ^ 64));            \
    }                                                                     \
    _Pragma("unroll")                                                     \
    for (int mi = 0; mi < 4; ++mi)                                        \
      _Pragma("unroll")                                                   \
      for (int ni = 0; ni < 4; ++ni)                                      \
        acc[mi][ni] = __builtin_amdgcn_mfma_f32_16x16x32_bf16(            \
            aF0[mi], bF0[ni], acc[mi][ni], 0, 0, 0);                      \
    _Pragma("unroll")                                                     \
    for (int mi = 0; mi < 4; ++mi)                                        \
      _Pragma("unroll")                                                   \
      for (int ni = 0; ni < 4; ++ni)                                      \
        acc[mi][ni] = __builtin_amdgcn_mfma_f32_16x16x32_bf16(            \
            aF1[mi], bF1[ni], acc[mi][ni], 0, 0, 0);                      \
  }

  // prologue: tile 0 -> LDS buf0; P=tile1, Q=tile2
  LDP(0)
  CVT_WR(0, P0, P1, P2, P3)
  LDP(1)
  LDQ(2)
  __syncthreads();

  const int NT = DIM / 64;                // 16
#pragma unroll 1
  for (int t = 0; t < NT; t += 2) {
    // even step: read buf0, fill buf1 with tile t+1 (P, loaded at t-2)
    COMPUTE(t, 0)
    CVT_WR(1, P0, P1, P2, P3)
    if (t + 3 < NT) LDP(t + 3)
    __syncthreads();
    // odd step: read buf1, fill buf0 with tile t+2 (Q, loaded at t-1)
    COMPUTE(t + 1, 1)
    if (t + 2 < NT) {
      CVT_WR(0, Q0, Q1, Q2, Q3)
      if (t + 4 < NT) LDQ(t + 4)
    }
    __syncthreads();
  }
#undef LDP
#undef LDQ
#undef CVT_WR
#undef COMPUTE

#pragma unroll
  for (int mi = 0; mi < 4; ++mi)
#pragma unroll
    for (int ni = 0; ni < 4; ++ni) {
      int n = n0 + ni * 16 + l16;
      if (n < VOC) {
#pragma unroll
        for (int r = 0; r < 4; ++r) {
          int s = wave * 64 + mi * 16 + quad * 4 + r;
          out[(long)s * VOC + n] = acc[mi][ni][r];
        }
      }
    }
}

extern "C" void kernel_launch(void* const* d_in, const int* in_sizes, int n_in,
                              void* d_out, int out_size, void* d_ws, size_t ws_size,
                              hipStream_t stream) {
  const int*   input_id = (const int*)d_in[0];
  const void*  reset    = d_in[1];
  const float* surprise = (const float*)d_in[2];
  const float* wm_state = (const float*)d_in[3];
  const float* h_state  = (const float*)d_in[4];
  const float* emb      = (const float*)d_in[5];
  const float* W_in     = (const float*)d_in[6];
  const float* W_alpha  = (const float*)d_in[7];
  const float* W_wm_out = (const float*)d_in[8];
  const float* W_x      = (const float*)d_in[9];
  const float* W_h      = (const float*)d_in[10];
  const float* W_wml    = (const float*)d_in[11];
  const float* W_g      = (const float*)d_in[12];
  const float* w_s      = (const float*)d_in[13];
  const float* b_g      = (const float*)d_in[14];

  float* out  = (float*)d_out;
  float* xout = out + (size_t)BSZ * VOC;          // x output (fp32, exact)
  float* yout = xout + (size_t)BSZ * DIM;         // y_wm output

  // Scratch lives in the logits region of d_out (only read before k_logits).
  const long SD = (long)BSZ * DIM;                // 262144
  u16* scr    = (u16*)d_out;
  u16* x_bf   = scr;                              // 256x1024
  u16* wm_bf  = scr + SD;
  u16* cur_bf = scr + 2 * SD;
  u16* ywm_bf = scr + 3 * SD;
  u16* h_bf   = scr + 4 * SD;                     // 2x256x1024

  // h_final + carry live OUTSIDE d_out (read while k_logits writes d_out)
  float* carry  = (float*)d_ws;
  u16* hfin_bf  = (u16*)((char*)d_ws + 1024);
  float* sink   = (float*)((char*)d_ws + 600 * 1024);

  k_prep<<<BSZ, 256, 0, stream>>>(input_id, reset, emb, h_state,
                                  W_alpha, W_in, W_wm_out, W_x, W_h, W_wml, W_g,
                                  xout, x_bf, h_bf, carry, sink);
  k_gemm1<<<512, 64, 0, stream>>>(x_bf, W_alpha, W_in, carry, wm_state, xout, wm_bf, cur_bf);
  k_gemm2<<<256, 64, 0, stream>>>(wm_bf, W_wm_out, yout, ywm_bf);
  k_layers<<<128, 512, 0, stream>>>(cur_bf, h_bf, ywm_bf, W_x, W_h, W_wml, W_g,
                                    w_s, b_g, surprise, carry, h_state, hfin_bf);
  k_logits_lds<<<(VOC + 63) / 64, 256, 0, stream>>>(hfin_bf, emb, out);
}

// Round 4
// 453.735 us; speedup vs baseline: 1.0637x; 1.0637x over previous
//
#include <hip/hip_runtime.h>
#include <math.h>

#define BSZ 256
#define DIM 1024
#define VOC 50257
#define NL 2
#define NB 8
#define DH 128

typedef __bf16 bf16x8 __attribute__((ext_vector_type(8)));
typedef float  f32x4  __attribute__((ext_vector_type(4)));
typedef unsigned short u16;
typedef unsigned int u32;
typedef u16 u16x8 __attribute__((ext_vector_type(8)));

__device__ __forceinline__ u16 f2bf(float f) {
  unsigned int u = __float_as_uint(f);
  u += 0x7fffu + ((u >> 16) & 1u);   // RNE
  return (u16)(u >> 16);
}
__device__ __forceinline__ float sigm(float x) { return 1.0f / (1.0f + __expf(-x)); }

// f32x8 -> bf16x8, hardware RNE (bit-identical to f2bf)
__device__ __forceinline__ bf16x8 cvt8(float4 a, float4 b) {
  bf16x8 r;
  r[0] = (__bf16)a.x; r[1] = (__bf16)a.y; r[2] = (__bf16)a.z; r[3] = (__bf16)a.w;
  r[4] = (__bf16)b.x; r[5] = (__bf16)b.y; r[6] = (__bf16)b.z; r[7] = (__bf16)b.w;
  return r;
}

// async global->LDS DMA, 16 B per lane; lds dst is wave-uniform base (+lane*16 by HW)
__device__ __forceinline__ void gld16(const float* g, float* l) {
  __builtin_amdgcn_global_load_lds(
      (const __attribute__((address_space(1))) u32*)(g),
      (__attribute__((address_space(3))) u32*)(l), 16, 0, 0);
}

// ---------------------------------------------------------------------------
// Barrier-free per-wave GEMM: acc[M16][N16] += A(bf16, row-major lda) *
// B(fp32, row-major ldb)^T. Fragments loaded directly from global in MFMA
// operand layout. 4-stage register pipeline. Requires K % 128 == 0.
// ---------------------------------------------------------------------------
template<int M16, int N16, int K, bool CLAMPN>
__device__ __forceinline__ void wave_gemm(
    const u16* __restrict__ A, int lda,
    const float* __restrict__ B, int ldb, int nClamp,
    f32x4 (&acc)[M16][N16])
{
  const int lane = threadIdx.x & 63;
  const int quad = lane >> 4;
  const int l16  = lane & 15;

  const u16* aR[M16];
  const float* bR[N16];
#pragma unroll
  for (int mi = 0; mi < M16; ++mi)
    aR[mi] = A + (long)(mi * 16 + l16) * lda + quad * 8;
#pragma unroll
  for (int ni = 0; ni < N16; ++ni) {
    int n = ni * 16 + l16;
    if (CLAMPN) n = n > nClamp ? nClamp : n;   // clamp addr; result discarded
    bR[ni] = B + (long)n * ldb + quad * 8;
  }

  bf16x8 aF[4][M16];
  bf16x8 bF[4][N16];

#define WG_LOAD(kk, buf)                                                  \
  {                                                                       \
    _Pragma("unroll")                                                     \
    for (int ni = 0; ni < N16; ++ni) {                                    \
      float4 v0 = *(const float4*)(bR[ni] + (kk));                        \
      float4 v1 = *(const float4*)(bR[ni] + (kk) + 4);                    \
      u16x8 h;                                                            \
      h[0] = f2bf(v0.x); h[1] = f2bf(v0.y);                               \
      h[2] = f2bf(v0.z); h[3] = f2bf(v0.w);                               \
      h[4] = f2bf(v1.x); h[5] = f2bf(v1.y);                               \
      h[6] = f2bf(v1.z); h[7] = f2bf(v1.w);                               \
      bF[buf][ni] = __builtin_bit_cast(bf16x8, h);                        \
    }                                                                     \
    _Pragma("unroll")                                                     \
    for (int mi = 0; mi < M16; ++mi)                                      \
      aF[buf][mi] = *(const bf16x8*)(aR[mi] + (kk));                      \
  }

#define WG_MM(buf)                                                        \
  {                                                                       \
    _Pragma("unroll")                                                     \
    for (int mi = 0; mi < M16; ++mi)                                      \
      _Pragma("unroll")                                                   \
      for (int ni = 0; ni < N16; ++ni)                                    \
        acc[mi][ni] = __builtin_amdgcn_mfma_f32_16x16x32_bf16(            \
            aF[buf][mi], bF[buf][ni], acc[mi][ni], 0, 0, 0);              \
  }

  WG_LOAD(0, 0);
  WG_LOAD(32, 1);
  WG_LOAD(64, 2);
#pragma unroll 1
  for (int kk = 0; kk < K - 128; kk += 128) {
    WG_LOAD(kk + 96, 3);  WG_MM(0);
    WG_LOAD(kk + 128, 0); WG_MM(1);
    WG_LOAD(kk + 160, 1); WG_MM(2);
    WG_LOAD(kk + 192, 2); WG_MM(3);
  }
  WG_LOAD(K - 32, 3);
  WG_MM(0); WG_MM(1); WG_MM(2); WG_MM(3);
#undef WG_LOAD
#undef WG_MM
}

#define ACC_DECL(N16V)                                \
  f32x4 acc[4][N16V];                                 \
  { f32x4 z = {0.f, 0.f, 0.f, 0.f};                   \
    _Pragma("unroll")                                 \
    for (int i = 0; i < 4; ++i)                       \
      _Pragma("unroll")                               \
      for (int j = 0; j < N16V; ++j) acc[i][j] = z; }

// ---------------------------------------------------------------------------
// K1: carry (bool-layout detect), x gather, h->bf16, + LLC warm of all weights
// ---------------------------------------------------------------------------
__global__ __launch_bounds__(256) void k_prep(
    const int* __restrict__ ids, const void* __restrict__ mask,
    const float* __restrict__ emb, const float* __restrict__ hstate,
    const float* __restrict__ W_alpha, const float* __restrict__ W_in,
    const float* __restrict__ W_wm_out, const float* __restrict__ W_x,
    const float* __restrict__ W_h, const float* __restrict__ W_wml,
    const float* __restrict__ W_g,
    float* __restrict__ xout, u16* __restrict__ x_bf,
    u16* __restrict__ h_bf, float* __restrict__ carry, float* __restrict__ sink)
{
  __shared__ int sInt;
  const int tid = threadIdx.x, s = blockIdx.x;
  if (tid == 0) sInt = 1;
  __syncthreads();
  if (tid < 64) {
    int v = ((const int*)mask)[tid];
    if (v != 0 && v != 1) atomicAnd(&sInt, 0);
  }
  __syncthreads();
  if (tid == 0) {
    int m = sInt ? ((const int*)mask)[s] : (int)((const unsigned char*)mask)[s];
    carry[s] = m ? 0.0f : 1.0f;
  }
  long id = ids[s];
  int k = tid * 4;
  float4 v = *(const float4*)(emb + id * DIM + k);
  *(float4*)(xout + (long)s * DIM + k) = v;
  ushort4 h; h.x = f2bf(v.x); h.y = f2bf(v.y); h.z = f2bf(v.z); h.w = f2bf(v.w);
  *(ushort4*)(x_bf + (long)s * DIM + k) = h;
#pragma unroll
  for (int l = 0; l < NL; ++l) {
    long off = (long)l * BSZ * DIM + (long)s * DIM + k;
    float4 w = *(const float4*)(hstate + off);
    ushort4 o; o.x = f2bf(w.x); o.y = f2bf(w.y); o.z = f2bf(w.z); o.w = f2bf(w.w);
    *(ushort4*)(h_bf + off) = o;
  }
  // ---- LLC warm (loads can't be eliminated; branch never taken) ----
  long gtid = (long)blockIdx.x * 256 + tid;
  long gstride = (long)gridDim.x * 256;
  float acc = 0.f;
  {
    const long nDD = (long)DIM * DIM / 4;       // 1024x1024 f32 -> float4 count
    for (long i = gtid; i < nDD; i += gstride) {
      float4 a = ((const float4*)W_alpha)[i];
      float4 b = ((const float4*)W_in)[i];
      float4 c = ((const float4*)W_wm_out)[i];
      acc += a.x + a.w + b.x + b.w + c.x + c.w;
    }
    const long nS = (long)NL * NB * DH * DH / 4;
    for (long i = gtid; i < nS; i += gstride) {
      float4 a = ((const float4*)W_x)[i];
      float4 b = ((const float4*)W_h)[i];
      float4 c = ((const float4*)W_g)[i];
      acc += a.x + a.w + b.x + b.w + c.x + c.w;
    }
    const long nW = (long)NL * NB * DH * DIM / 4;
    for (long i = gtid; i < nW; i += gstride) {
      float4 a = ((const float4*)W_wml)[i];
      acc += a.x + a.w;
    }
  }
  if (acc == -1.17521e35f) *sink = acc;   // never true in practice; defeats DCE
}

// ---------------------------------------------------------------------------
// K2: [alpha_pre | x_proj] = x @ [W_alpha ; W_in]^T, fused wm_new epilogue
// 512 blocks x 64 threads: m-slice = blk&3, n-tile16 = blk>>2 (128 tiles)
// ---------------------------------------------------------------------------
__global__ __launch_bounds__(64) void k_gemm1(
    const u16* __restrict__ x_bf,
    const float* __restrict__ W_alpha, const float* __restrict__ W_in,
    const float* __restrict__ carry, const float* __restrict__ wm_state,
    const float* __restrict__ xout,
    u16* __restrict__ wm_bf, u16* __restrict__ cur_bf)
{
  const int tid = threadIdx.x, quad = tid >> 4, l16 = tid & 15;
  const int m = blockIdx.x & 3;
  const int nt = blockIdx.x >> 2;
  const bool isAlpha = nt < 64;
  const int n0 = (isAlpha ? nt : nt - 64) * 16;
  ACC_DECL(1)
  wave_gemm<4, 1, DIM, false>(x_bf + (long)m * 64 * DIM, DIM,
                              (isAlpha ? W_alpha : W_in) + (long)n0 * DIM, DIM, 0, acc);
#pragma unroll
  for (int mi = 0; mi < 4; ++mi) {
    int n = n0 + l16;
#pragma unroll
    for (int r = 0; r < 4; ++r) {
      int s = m * 64 + mi * 16 + quad * 4 + r;
      float c = acc[mi][0][r];
      long idx = (long)s * DIM + n;
      if (isAlpha) wm_bf[idx] = f2bf(carry[s] * sigm(c) * wm_state[idx] + xout[idx]);
      else         cur_bf[idx] = f2bf(c);
    }
  }
}

// ---------------------------------------------------------------------------
// K3: y_wm = tanh(wm_new @ W_wm_out^T)   (256 blocks x 64 threads)
// ---------------------------------------------------------------------------
__global__ __launch_bounds__(64) void k_gemm2(
    const u16* __restrict__ wm_bf, const float* __restrict__ W_wm_out,
    float* __restrict__ yout, u16* __restrict__ ywm_bf)
{
  const int tid = threadIdx.x, quad = tid >> 4, l16 = tid & 15;
  const int m = blockIdx.x & 3;
  const int n0 = (blockIdx.x >> 2) * 16;
  ACC_DECL(1)
  wave_gemm<4, 1, DIM, false>(wm_bf + (long)m * 64 * DIM, DIM,
                              W_wm_out + (long)n0 * DIM, DIM, 0, acc);
#pragma unroll
  for (int mi = 0; mi < 4; ++mi) {
    int n = n0 + l16;
#pragma unroll
    for (int r = 0; r < 4; ++r) {
      int s = m * 64 + mi * 16 + quad * 4 + r;
      float y = tanhf(acc[mi][0][r]);
      long idx = (long)s * DIM + n;
      yout[idx] = y;
      ywm_bf[idx] = f2bf(y);
    }
  }
}

// ---------------------------------------------------------------------------
// K4/K6: a = cur@W_x^T + h@W_h^T + y_wm@W_wml^T
// 256 blocks x 64 threads: m = blk&3, nt = blk>>2 (64 e-tiles: b = nt>>3)
// (R2's measured-best middle structure: 256 single-wave blocks = full CU
// coverage; M16=4 amortizes B loads. The R3 fusion regressed both.)
// ---------------------------------------------------------------------------
__global__ __launch_bounds__(64) void k_gemm_a(
    int l, const u16* __restrict__ cur_bf, const u16* __restrict__ h_bf,
    const u16* __restrict__ ywm_bf,
    const float* __restrict__ W_x, const float* __restrict__ W_h,
    const float* __restrict__ W_wml,
    float* __restrict__ a_f32, u16* __restrict__ a_bf)
{
  const int tid = threadIdx.x, quad = tid >> 4, l16 = tid & 15;
  const int m = blockIdx.x & 3;
  const int nt = blockIdx.x >> 2;
  const int b = nt >> 3;
  const int e0 = (nt & 7) * 16;
  ACC_DECL(1)
  const long moff = (long)m * 64 * DIM;
  wave_gemm<4, 1, DH, false>(cur_bf + moff + b * DH, DIM,
                             W_x + ((long)(l * NB + b) * DH + e0) * DH, DH, 0, acc);
  wave_gemm<4, 1, DH, false>(h_bf + (long)l * BSZ * DIM + moff + b * DH, DIM,
                             W_h + ((long)(l * NB + b) * DH + e0) * DH, DH, 0, acc);
  wave_gemm<4, 1, DIM, false>(ywm_bf + moff, DIM,
                              W_wml + ((long)(l * NB + b) * DH + e0) * DIM, DIM, 0, acc);
#pragma unroll
  for (int mi = 0; mi < 4; ++mi) {
    int e = e0 + l16;
#pragma unroll
    for (int r = 0; r < 4; ++r) {
      int s = m * 64 + mi * 16 + quad * 4 + r;
      float c = acc[mi][0][r];
      long idx = (long)s * DIM + b * DH + e;
      a_f32[idx] = c;
      a_bf[idx] = f2bf(c);
    }
  }
}

// ---------------------------------------------------------------------------
// K5/K7: g = sigmoid(a@W_g^T + surprise*w_s + b_g); h_new gating
// ---------------------------------------------------------------------------
__global__ __launch_bounds__(64) void k_gemm_g(
    int l, const u16* __restrict__ a_bf, const float* __restrict__ W_g,
    const float* __restrict__ w_s, const float* __restrict__ b_g,
    const float* __restrict__ surprise, const float* __restrict__ carry,
    const float* __restrict__ hstate, const float* __restrict__ a_f32,
    u16* __restrict__ hout_bf)
{
  const int tid = threadIdx.x, quad = tid >> 4, l16 = tid & 15;
  const int m = blockIdx.x & 3;
  const int nt = blockIdx.x >> 2;
  const int b = nt >> 3;
  const int e0 = (nt & 7) * 16;
  ACC_DECL(1)
  wave_gemm<4, 1, DH, false>(a_bf + (long)m * 64 * DIM + b * DH, DIM,
                             W_g + ((long)(l * NB + b) * DH + e0) * DH, DH, 0, acc);
#pragma unroll
  for (int mi = 0; mi < 4; ++mi) {
    int e = e0 + l16;
#pragma unroll
    for (int r = 0; r < 4; ++r) {
      int s = m * 64 + mi * 16 + quad * 4 + r;
      float c = acc[mi][0][r];
      long idx = (long)s * DIM + b * DH + e;
      float gp = c + surprise[s] * w_s[(l * NB + b) * DH + e] + b_g[(l * NB + b) * DH + e];
      float g = sigm(gp);
      float ho = hstate[(long)l * BSZ * DIM + idx];
      float hn = carry[s] * ((1.0f - g) * ho + g * tanhf(a_f32[idx]));
      hout_bf[idx] = f2bf(hn);
    }
  }
}

// ---------------------------------------------------------------------------
// K8: logits = h_final @ emb^T — global_load_lds staging, f32 tiles in LDS,
// read-side f32->bf16 convert. 786 blocks x 256 threads (4 waves), 64 vocab
// cols x 64 K per tile, 2 x 16 KB LDS double buffer, ONE barrier per tile.
//
// Why this structure (R1-R3 post-mortems): reg-staged pipelines stalled
// ~90% regardless of depth — the CVT's register dependence + __syncthreads'
// full fence serialize staging with compute. global_load_lds is
// fire-and-forget DMA: no regs, no stage-side VALU; the end-of-iteration
// barrier's vmcnt(0) drain is the only wait, and a full compute phase of
// latency cover sits in front of it (m97 pattern).
//
// LDS swizzle with a LINEAR DMA destination is done by pre-swizzling the
// GLOBAL source (m173): LDS(r, c16) holds global 16B chunk (c16 ^ (r&15))
// of vocab row n0+r; reads XOR the same way. A-loads are issued BEFORE the
// staging DMAs so the MFMA's wait is vmcnt(4), not vmcnt(0).
// ---------------------------------------------------------------------------
__global__ __launch_bounds__(256) void k_logits_gl(
    const u16* __restrict__ hfin_bf, const float* __restrict__ emb,
    float* __restrict__ out)
{
  __shared__ float Bs[2][64 * 64];        // 2 x 16 KB f32 tiles
  const int tid  = threadIdx.x;
  const int wave = tid >> 6;
  const int lane = tid & 63;
  const int quad = lane >> 4;
  const int l16  = lane & 15;
  const int n0   = blockIdx.x * 64;

  // staging: wave w owns LDS rows w*16..+15; DMA j covers rows w*16+j*4..+3.
  // lane -> (row = base + lane>>4, chunk = lane&15); HW dest = base + lane*16.
  const float* srcP[4];
#pragma unroll
  for (int j = 0; j < 4; ++j) {
    int r = wave * 16 + j * 4 + (lane >> 4);
    int c = (lane & 15) ^ (r & 15);       // inverse swizzle on the source
    long gn = n0 + r; if (gn > VOC - 1) gn = VOC - 1;  // tail clamp (dups discarded)
    srcP[j] = emb + gn * DIM + c * 4;
  }
  float* const dst0 = &Bs[0][wave * 16 * 64];

  const u16* aP[4];
#pragma unroll
  for (int mi = 0; mi < 4; ++mi)
    aP[mi] = hfin_bf + (long)(wave * 64 + mi * 16 + l16) * DIM + quad * 8;

  f32x4 acc[4][4];
  { f32x4 z = {0.f, 0.f, 0.f, 0.f};
#pragma unroll
    for (int mi = 0; mi < 4; ++mi)
#pragma unroll
      for (int ni = 0; ni < 4; ++ni) acc[mi][ni] = z; }

#define STAGE(bufi, t)                                                    \
  { _Pragma("unroll")                                                     \
    for (int j = 0; j < 4; ++j)                                           \
      gld16(srcP[j] + (t) * 64, dst0 + (bufi) * 4096 + j * 256); }

  STAGE(0, 0)
  __syncthreads();                        // drain DMA of tile 0

  const int NT = DIM / 64;                // 16
#pragma unroll 1
  for (int t = 0; t < NT; ++t) {
    const int k0 = t * 64;
    // A frags first: MFMA's vmem wait becomes vmcnt(4) (4 DMAs younger)
    bf16x8 aF0[4], aF1[4];
#pragma unroll
    for (int mi = 0; mi < 4; ++mi) aF0[mi] = *(const bf16x8*)(aP[mi] + k0);
#pragma unroll
    for (int mi = 0; mi < 4; ++mi) aF1[mi] = *(const bf16x8*)(aP[mi] + k0 + 32);
    if (t + 1 < NT) { STAGE((t + 1) & 1, t + 1) }

    const char* bb = (const char*)&Bs[t & 1][0];
    bf16x8 bF0[4], bF1[4];
#pragma unroll
    for (int ni = 0; ni < 4; ++ni) {
      const char* rb = bb + (ni * 16 + l16) * 256;
      float4 u0 = *(const float4*)(rb + (((quad * 2)     ^ l16) << 4));
      float4 u1 = *(const float4*)(rb + (((quad * 2 + 1) ^ l16) << 4));
      float4 w0 = *(const float4*)(rb + (((quad * 2 + 8) ^ l16) << 4));
      float4 w1 = *(const float4*)(rb + (((quad * 2 + 9) ^ l16) << 4));
      bF0[ni] = cvt8(u0, u1);
      bF1[ni] = cvt8(w0, w1);
    }
#pragma unroll
    for (int mi = 0; mi < 4; ++mi)
#pragma unroll
      for (int ni = 0; ni < 4; ++ni)
        acc[mi][ni] = __builtin_amdgcn_mfma_f32_16x16x32_bf16(
            aF0[mi], bF0[ni], acc[mi][ni], 0, 0, 0);
#pragma unroll
    for (int mi = 0; mi < 4; ++mi)
#pragma unroll
      for (int ni = 0; ni < 4; ++ni)
        acc[mi][ni] = __builtin_amdgcn_mfma_f32_16x16x32_bf16(
            aF1[mi], bF1[ni], acc[mi][ni], 0, 0, 0);

    __syncthreads();   // one barrier/tile: drains next-tile DMA + seals reads
  }
#undef STAGE

#pragma unroll
  for (int mi = 0; mi < 4; ++mi)
#pragma unroll
    for (int ni = 0; ni < 4; ++ni) {
      int n = n0 + ni * 16 + l16;
      if (n < VOC) {
#pragma unroll
        for (int r = 0; r < 4; ++r) {
          int s = wave * 64 + mi * 16 + quad * 4 + r;
          out[(long)s * VOC + n] = acc[mi][ni][r];
        }
      }
    }
}

extern "C" void kernel_launch(void* const* d_in, const int* in_sizes, int n_in,
                              void* d_out, int out_size, void* d_ws, size_t ws_size,
                              hipStream_t stream) {
  const int*   input_id = (const int*)d_in[0];
  const void*  reset    = d_in[1];
  const float* surprise = (const float*)d_in[2];
  const float* wm_state = (const float*)d_in[3];
  const float* h_state  = (const float*)d_in[4];
  const float* emb      = (const float*)d_in[5];
  const float* W_in     = (const float*)d_in[6];
  const float* W_alpha  = (const float*)d_in[7];
  const float* W_wm_out = (const float*)d_in[8];
  const float* W_x      = (const float*)d_in[9];
  const float* W_h      = (const float*)d_in[10];
  const float* W_wml    = (const float*)d_in[11];
  const float* W_g      = (const float*)d_in[12];
  const float* w_s      = (const float*)d_in[13];
  const float* b_g      = (const float*)d_in[14];

  float* out  = (float*)d_out;
  float* xout = out + (size_t)BSZ * VOC;          // x output (fp32, exact)
  float* yout = xout + (size_t)BSZ * DIM;         // y_wm output

  // Scratch lives in the logits region of d_out (only read before k_logits).
  const long SD = (long)BSZ * DIM;                // 262144
  u16* scr    = (u16*)d_out;
  u16* x_bf   = scr;                              // 256x1024
  u16* wm_bf  = scr + SD;
  u16* cur_bf = scr + 2 * SD;
  u16* ywm_bf = scr + 3 * SD;
  u16* h_bf   = scr + 4 * SD;                     // 2x256x1024
  u16* a_bf   = scr + 6 * SD;
  float* a_f32 = (float*)(scr + 8 * SD);          // 256x1024 fp32

  // h_final + carry live OUTSIDE d_out (read while k_logits writes d_out)
  float* carry  = (float*)d_ws;
  u16* hfin_bf  = (u16*)((char*)d_ws + 1024);
  float* sink   = (float*)((char*)d_ws + 600 * 1024);

  k_prep<<<BSZ, 256, 0, stream>>>(input_id, reset, emb, h_state,
                                  W_alpha, W_in, W_wm_out, W_x, W_h, W_wml, W_g,
                                  xout, x_bf, h_bf, carry, sink);
  k_gemm1<<<512, 64, 0, stream>>>(x_bf, W_alpha, W_in, carry, wm_state, xout, wm_bf, cur_bf);
  k_gemm2<<<256, 64, 0, stream>>>(wm_bf, W_wm_out, yout, ywm_bf);
  k_gemm_a<<<256, 64, 0, stream>>>(0, cur_bf, h_bf, ywm_bf, W_x, W_h, W_wml, a_f32, a_bf);
  k_gemm_g<<<256, 64, 0, stream>>>(0, a_bf, W_g, w_s, b_g, surprise, carry, h_state, a_f32, cur_bf);
  k_gemm_a<<<256, 64, 0, stream>>>(1, cur_bf, h_bf, ywm_bf, W_x, W_h, W_wml, a_f32, a_bf);
  k_gemm_g<<<256, 64, 0, stream>>>(1, a_bf, W_g, w_s, b_g, surprise, carry, h_state, a_f32, hfin_bf);
  k_logits_gl<<<(VOC + 63) / 64, 256, 0, stream>>>(hfin_bf, emb, out);
}